// Round 14
// baseline (770.592 us; speedup 1.0000x reference)
//
#include <hip/hip_runtime.h>
#include <stdint.h>

typedef unsigned short ushort_t;
typedef __attribute__((ext_vector_type(8))) short short8;
typedef __attribute__((ext_vector_type(8))) unsigned short u16x8;
typedef __attribute__((ext_vector_type(4))) float f32x4;

#define GLOBAL_AS __attribute__((address_space(1)))
#define LDS_AS __attribute__((address_space(3)))

__device__ __forceinline__ ushort_t f2bf(float f) {
  union { float f; uint32_t u; } v; v.f = f;
  uint32_t u = v.u;
  u += 0x7FFFu + ((u >> 16) & 1u);   // round-to-nearest-even
  return (ushort_t)(u >> 16);
}

// XOR swizzle for [R][64] bf16 LDS tiles (128B rows) in prep kernel.
__device__ __forceinline__ int swz(int row, int byteInRow) {
  return (row * 128 + byteInRow) ^ ((row & 7) << 4);
}

// ---------------- weight transpose + bf16 cast: dst[n][k] = bf16(src[k][n]); fout = 512 always
struct TransArgs {
  const float* src[8];
  ushort_t* dst[8];
  int K[8];
  int blk0[9];
};

__global__ __launch_bounds__(256) void transpose_weights(TransArgs ta) {
  __shared__ float tile[64 * 65];
  int b = blockIdx.x;
  int mi = 0;
#pragma unroll
  for (int i = 1; i < 8; ++i) if (b >= ta.blk0[i]) mi = i;
  const float* src = ta.src[mi];
  ushort_t* dst = ta.dst[mi];
  int K = ta.K[mi];
  int rel = b - ta.blk0[mi];
  int ktiles = K >> 6;
  int k0 = (rel % ktiles) << 6;
  int n0 = (rel / ktiles) << 6;
  int t = threadIdx.x;
#pragma unroll
  for (int i = 0; i < 16; ++i) {
    int idx = i * 256 + t;
    int r = idx >> 6, c = idx & 63;
    tile[r * 65 + c] = src[(size_t)(k0 + r) * 512 + (n0 + c)];
  }
  __syncthreads();
#pragma unroll
  for (int i = 0; i < 16; ++i) {
    int idx = i * 256 + t;
    int r = idx >> 6, c = idx & 63;          // r: n-row, c: k-col
    dst[(size_t)(n0 + r) * K + (k0 + c)] = f2bf(tile[c * 65 + r]);
  }
}

// ---------------- prep: X[e][0:512]=bf16(pred); pos[e][0:128] = 3-layer FCN via MFMA.
__global__ __launch_bounds__(256) void prep_kernel(
    const float* __restrict__ pred, const float* __restrict__ centroid,
    const float* __restrict__ pw1, const float* __restrict__ pb1,
    const float* __restrict__ pw2, const float* __restrict__ pb2,
    const float* __restrict__ pw3, const float* __restrict__ pb3,
    ushort_t* __restrict__ X, ushort_t* __restrict__ pos, int nm1)
{
  __shared__ ushort_t h1s[128 * 64];
  __shared__ ushort_t h2s[128 * 64];
  __shared__ ushort_t w2t[64 * 64];
  __shared__ ushort_t w3t[128 * 64];
  __shared__ float w1s[5 * 64];
  __shared__ float b1s[64], b2s[64], b3s[128];
  int t = threadIdx.x;
  for (int idx = t; idx < 64 * 64; idx += 256) {
    int k = idx >> 6, n = idx & 63;
    *(ushort_t*)((char*)w2t + swz(n, k * 2)) = f2bf(pw2[idx]);
  }
  for (int idx = t; idx < 64 * 128; idx += 256) {
    int k = idx >> 7, n = idx & 127;
    *(ushort_t*)((char*)w3t + swz(n, k * 2)) = f2bf(pw3[idx]);
  }
  for (int i = t; i < 5 * 64; i += 256) w1s[i] = pw1[i];
  if (t < 64) { b1s[t] = pb1[t]; b2s[t] = pb2[t]; }
  if (t < 128) b3s[t] = pb3[t];
  __syncthreads();   // race fix (r4)

  int wid = t >> 6, lane = t & 63;
  int ebase = blockIdx.x * 128 + wid * 32;
  for (int it = 0; it < 32; ++it) {
    int e = ebase + it;
    const float* pr = pred + (size_t)e * 512 + lane * 8;
    float4 pA = *(const float4*)pr;
    float4 pB = *(const float4*)(pr + 4);
    u16x8 o;
    o[0] = f2bf(pA.x); o[1] = f2bf(pA.y); o[2] = f2bf(pA.z); o[3] = f2bf(pA.w);
    o[4] = f2bf(pB.x); o[5] = f2bf(pB.y); o[6] = f2bf(pB.z); o[7] = f2bf(pB.w);
    *(u16x8*)(X + (size_t)e * 512 + lane * 8) = o;
    int i = e / nm1;
    int r = e - i * nm1;
    int j = r + (r >= i ? 1 : 0);
    float dx = centroid[i * 3 + 0] - centroid[j * 3 + 0];
    float dy = centroid[i * 3 + 1] - centroid[j * 3 + 1];
    float dist = sqrtf(dx * dx + dy * dy);
    float inv = 1.0f / dist;
    float h1 = w1s[0 * 64 + lane] * dx + w1s[1 * 64 + lane] * dy + w1s[2 * 64 + lane] * dist
             + w1s[3 * 64 + lane] * (dx * inv) + w1s[4 * 64 + lane] * (dy * inv) + b1s[lane];
    h1 = fmaxf(h1, 0.0f);
    int row = wid * 32 + it;
    *(ushort_t*)((char*)h1s + swz(row, lane * 2)) = f2bf(h1);
  }
  __syncthreads();

  int colg = lane & 15, rowg = (lane >> 4) << 2;
  int ko_lane = (lane >> 4) * 8;
  {
    f32x4 acc[2][4];
    f32x4 zero = {0.0f, 0.0f, 0.0f, 0.0f};
#pragma unroll
    for (int m_ = 0; m_ < 2; ++m_)
#pragma unroll
      for (int n_ = 0; n_ < 4; ++n_) acc[m_][n_] = zero;
#pragma unroll
    for (int kk = 0; kk < 2; ++kk) {
      int ko = kk * 32 + ko_lane;
      short8 a[2], b[4];
#pragma unroll
      for (int m_ = 0; m_ < 2; ++m_)
        a[m_] = *(const short8*)((const char*)h1s + swz(wid * 32 + m_ * 16 + colg, ko * 2));
#pragma unroll
      for (int n_ = 0; n_ < 4; ++n_)
        b[n_] = *(const short8*)((const char*)w2t + swz(n_ * 16 + colg, ko * 2));
#pragma unroll
      for (int m_ = 0; m_ < 2; ++m_)
#pragma unroll
        for (int n_ = 0; n_ < 4; ++n_)
          acc[m_][n_] = __builtin_amdgcn_mfma_f32_16x16x32_bf16(a[m_], b[n_], acc[m_][n_], 0, 0, 0);
    }
#pragma unroll
    for (int n_ = 0; n_ < 4; ++n_) {
      int col = n_ * 16 + colg;
      float bv = b2s[col];
#pragma unroll
      for (int m_ = 0; m_ < 2; ++m_) {
        int row = wid * 32 + m_ * 16 + rowg;
#pragma unroll
        for (int jj = 0; jj < 4; ++jj) {
          float v = fmaxf(acc[m_][n_][jj] + bv, 0.0f);
          *(ushort_t*)((char*)h2s + swz(row + jj, col * 2)) = f2bf(v);
        }
      }
    }
  }
  __syncthreads();
  {
    f32x4 acc[2][8];
    f32x4 zero = {0.0f, 0.0f, 0.0f, 0.0f};
#pragma unroll
    for (int m_ = 0; m_ < 2; ++m_)
#pragma unroll
      for (int n_ = 0; n_ < 8; ++n_) acc[m_][n_] = zero;
#pragma unroll
    for (int kk = 0; kk < 2; ++kk) {
      int ko = kk * 32 + ko_lane;
      short8 a[2], b[8];
#pragma unroll
      for (int m_ = 0; m_ < 2; ++m_)
        a[m_] = *(const short8*)((const char*)h2s + swz(wid * 32 + m_ * 16 + colg, ko * 2));
#pragma unroll
      for (int n_ = 0; n_ < 8; ++n_)
        b[n_] = *(const short8*)((const char*)w3t + swz(n_ * 16 + colg, ko * 2));
#pragma unroll
      for (int m_ = 0; m_ < 2; ++m_)
#pragma unroll
        for (int n_ = 0; n_ < 8; ++n_)
          acc[m_][n_] = __builtin_amdgcn_mfma_f32_16x16x32_bf16(a[m_], b[n_], acc[m_][n_], 0, 0, 0);
    }
#pragma unroll
    for (int n_ = 0; n_ < 8; ++n_) {
      int col = n_ * 16 + colg;
      float bv = b3s[col];
#pragma unroll
      for (int m_ = 0; m_ < 2; ++m_) {
        int row = wid * 32 + m_ * 16 + rowg;
#pragma unroll
        for (int jj = 0; jj < 4; ++jj) {
          int e = blockIdx.x * 128 + row + jj;
          pos[(size_t)e * 128 + col] = f2bf(acc[m_][n_][jj] + bv);
        }
      }
    }
  }
}

// ---------------- OLD 128x128 GEMM (fallback path only)
__global__ __launch_bounds__(256) void gemm_bias_relu(
    const void* __restrict__ A0, int lda0,
    const void* __restrict__ A1, int lda1,
    const void* __restrict__ A2, int lda2,
    int s0, int s1, int aF32,
    const ushort_t* __restrict__ Bt, const float* __restrict__ bias,
    void* __restrict__ Cout, int outF32, ushort_t* __restrict__ Cdual, int K)
{
  __shared__ ushort_t As[128 * 64];
  __shared__ ushort_t Bs[128 * 64];
  int bid = blockIdx.x;
  int cpx = gridDim.x >> 3;
  int swzb = (bid & 7) * cpx + (bid >> 3);
  int mt = swzb >> 2, nt = swzb & 3;
  int m0 = mt << 7, n0 = nt << 7;
  int t = threadIdx.x;
  int lane = t & 63, wid = t >> 6;
  int wm = wid >> 1, wn = wid & 1;
  f32x4 acc[4][4];
  f32x4 zero = {0.0f, 0.0f, 0.0f, 0.0f};
#pragma unroll
  for (int a_ = 0; a_ < 4; ++a_)
#pragma unroll
    for (int b_ = 0; b_ < 4; ++b_) acc[a_][b_] = zero;

  for (int kt = 0; kt < K; kt += 64) {
    const void* Ab; int ldaA; int kin;
    if (kt < s0)      { Ab = A0; ldaA = lda0; kin = kt; }
    else if (kt < s1) { Ab = A1; ldaA = lda1; kin = kt - s0; }
    else              { Ab = A2; ldaA = lda2; kin = kt - s1; }
    if (aF32) {
      const float* Af = (const float*)Ab;
      int rr = t >> 1, cc0 = (t & 1) << 5;
      const float* g = Af + (size_t)(m0 + rr) * ldaA + kin + cc0;
      ushort_t* ldst = As + rr * 64 + cc0;
#pragma unroll
      for (int i = 0; i < 4; ++i) {
        float4 v0 = *(const float4*)(g + i * 8);
        float4 v1 = *(const float4*)(g + i * 8 + 4);
        u16x8 o;
        o[0] = f2bf(v0.x); o[1] = f2bf(v0.y); o[2] = f2bf(v0.z); o[3] = f2bf(v0.w);
        o[4] = f2bf(v1.x); o[5] = f2bf(v1.y); o[6] = f2bf(v1.z); o[7] = f2bf(v1.w);
        *(u16x8*)(ldst + i * 8) = o;
      }
    } else {
      const ushort_t* Ah = (const ushort_t*)Ab;
#pragma unroll
      for (int i = 0; i < 4; ++i) {
        int ch = i * 256 + t;
        int rr = ch >> 3, cc = (ch & 7) << 3;
        const ushort_t* g = Ah + (size_t)(m0 + rr) * ldaA + kin + cc;
        __builtin_amdgcn_global_load_lds((const GLOBAL_AS void*)g,
                                         (LDS_AS void*)(As + ch * 8), 16, 0, 0);
      }
    }
#pragma unroll
    for (int i = 0; i < 4; ++i) {
      int ch = i * 256 + t;
      int rr = ch >> 3, cc = (ch & 7) << 3;
      const ushort_t* g = Bt + (size_t)(n0 + rr) * K + kt + cc;
      __builtin_amdgcn_global_load_lds((const GLOBAL_AS void*)g,
                                       (LDS_AS void*)(Bs + ch * 8), 16, 0, 0);
    }
    __syncthreads();
#pragma unroll
    for (int kk = 0; kk < 64; kk += 32) {
      int ko = kk + (lane >> 4) * 8;
      short8 a[4], b[4];
#pragma unroll
      for (int m_ = 0; m_ < 4; ++m_)
        a[m_] = *(const short8*)(As + (wm * 64 + m_ * 16 + (lane & 15)) * 64 + ko);
#pragma unroll
      for (int n_ = 0; n_ < 4; ++n_)
        b[n_] = *(const short8*)(Bs + (wn * 64 + n_ * 16 + (lane & 15)) * 64 + ko);
#pragma unroll
      for (int m_ = 0; m_ < 4; ++m_)
#pragma unroll
        for (int n_ = 0; n_ < 4; ++n_)
          acc[m_][n_] = __builtin_amdgcn_mfma_f32_16x16x32_bf16(a[m_], b[n_], acc[m_][n_], 0, 0, 0);
    }
    __syncthreads();
  }
  int colg = lane & 15, rowg = (lane >> 4) << 2;
  float* C32 = (float*)Cout;
  ushort_t* C16 = (ushort_t*)Cout;
#pragma unroll
  for (int n_ = 0; n_ < 4; ++n_) {
    int col = n0 + wn * 64 + n_ * 16 + colg;
    float bv = bias[col];
#pragma unroll
    for (int m_ = 0; m_ < 4; ++m_) {
      int row = m0 + wm * 64 + m_ * 16 + rowg;
#pragma unroll
      for (int jj = 0; jj < 4; ++jj) {
        float v = fmaxf(acc[m_][n_][jj] + bv, 0.0f);
        if (outF32) C32[(size_t)(row + jj) * 512 + col] = v;
        else        C16[(size_t)(row + jj) * 512 + col] = f2bf(v);
        if (Cdual)  Cdual[(size_t)(row + jj) * 512 + col] = f2bf(v);
      }
    }
  }
}

// ---------------- Multi-job GEMM, ring-3 flight-2 (fast path).
// r13 core with ONE change: LDS ring deepened 2 -> 3 (72 KiB, still 2
// blocks/CU) so the boundary wait covers ~2 iterations of latency instead
// of 1. Ledger: prologue stages tiles 0..2, vmcnt(6); iter tt: compute(tt),
// barrier, stage(tt+3) into buf[tt%3] (WAR-safe), wait tile tt+1 via taper
// vmcnt(6/3/0), barrier. Same K order -> bit-identical numerics.
struct GJob {
  const ushort_t* A0; const ushort_t* A1; const ushort_t* A2;
  const ushort_t* Bt; const float* bias;
  void* Cout; ushort_t* Cdual;
  int lda0, lda1, lda2, s0, s1, K, outF32;
};
struct GJobs { GJob j[3]; int blk0[4]; };

__global__ __launch_bounds__(512, 4) void gemm_jobs(GJobs J) {
  __shared__ char As[3 * 8192];              // [tile%3][128 rows][32 bf16]
  __shared__ char Bs[3 * 16384];             // [tile%3][256 n-rows][32 bf16]
  int bid = blockIdx.x;
  int ji = 0;
  if (bid >= J.blk0[1]) ji = 1;
  if (bid >= J.blk0[2]) ji = 2;
  const GJob jb = J.j[ji];
  int rel = bid - J.blk0[ji];
  int nwg = J.blk0[ji + 1] - J.blk0[ji];
  int q = nwg >> 3, r8_ = nwg & 7;
  int xcd = rel & 7, ii = rel >> 3;
  int sid = (xcd < r8_ ? xcd * (q + 1) : r8_ * (q + 1) + (xcd - r8_) * q) + ii;
  int mt = sid >> 1, nt = sid & 1;           // consecutive sids share mt
  int m0 = mt << 7, n0 = nt << 8;
  int t = threadIdx.x;
  int lane = t & 63, wid = t >> 6;
  int wm = wid >> 2, wn = wid & 3;           // wave tile: rows wm*64, cols wn*64
  int g = lane >> 4, l15 = lane & 15;
  int K = jb.K;

  f32x4 acc[4][4];
  f32x4 zero = {0.0f, 0.0f, 0.0f, 0.0f};
#pragma unroll
  for (int mf = 0; mf < 4; ++mf)
#pragma unroll
    for (int nf = 0; nf < 4; ++nf) acc[mf][nf] = zero;

  auto stage = [&](int tile, int slot) {     // 3 wave-level gload_lds total
    int kt = tile << 5;
    const ushort_t* src; int ld; int kin;
    if (kt < jb.s0)      { src = jb.A0; ld = jb.lda0; kin = kt; }
    else if (kt < jb.s1) { src = jb.A1; ld = jb.lda1; kin = kt - jb.s0; }
    else                 { src = jb.A2; ld = jb.lda2; kin = kt - jb.s1; }
    char* Ad = As + slot * 8192;
    {
      int c = t;                             // 512 chunks of 16B; lane-contiguous
      int row = c >> 2;
      int sl = (c & 3) ^ (row & 3);          // inverse-swizzled source slot
      const ushort_t* gp = src + (size_t)(m0 + row) * ld + kin + sl * 8;
      __builtin_amdgcn_global_load_lds((const GLOBAL_AS void*)gp,
          (LDS_AS void*)(Ad + c * 16), 16, 0, 0);
    }
    char* Bd = Bs + slot * 16384;
#pragma unroll
    for (int L = 0; L < 2; ++L) {
      int c = wid * 128 + L * 64 + lane;     // 1024 chunks; lane-contiguous
      int row = c >> 2;
      int sl = (c & 3) ^ (row & 3);
      const ushort_t* gp = jb.Bt + (size_t)(n0 + row) * K + kt + sl * 8;
      __builtin_amdgcn_global_load_lds((const GLOBAL_AS void*)gp,
          (LDS_AS void*)(Bd + c * 16), 16, 0, 0);
    }
  };

  // prologue: 3 tiles in flight; own tile-0 loads done when 6 newer remain
  int NT = K >> 5;                           // NT >= 16 for all our launches
  stage(0, 0); stage(1, 1); stage(2, 2);
  asm volatile("s_waitcnt vmcnt(6)" ::: "memory");
  __builtin_amdgcn_s_barrier();              // tile 0 visible to all waves
  __builtin_amdgcn_sched_barrier(0);

  int slot = 0;                              // slot = tt % 3
  for (int tt = 0; tt < NT; ++tt) {
    const char* Ab = As + slot * 8192;
    const char* Bb = Bs + slot * 16384;
    short8 a[4], b[4];
#pragma unroll
    for (int nf = 0; nf < 4; ++nf) {
      int r = wn * 64 + nf * 16 + l15;
      b[nf] = *(const short8*)(Bb + r * 64 + ((g * 16) ^ ((r & 3) << 4)));
    }
#pragma unroll
    for (int mf = 0; mf < 4; ++mf) {
      int r = wm * 64 + mf * 16 + l15;
      a[mf] = *(const short8*)(Ab + r * 64 + ((g * 16) ^ ((r & 3) << 4)));
    }
    __builtin_amdgcn_s_setprio(1);
#pragma unroll
    for (int mf = 0; mf < 4; ++mf)
#pragma unroll
      for (int nf = 0; nf < 4; ++nf)
        acc[mf][nf] = __builtin_amdgcn_mfma_f32_16x16x32_bf16(a[mf], b[nf], acc[mf][nf], 0, 0, 0);
    __builtin_amdgcn_s_setprio(0);
    __builtin_amdgcn_sched_barrier(0);
    if (tt + 1 < NT) {
      __builtin_amdgcn_s_barrier();          // all waves done reading buf[slot]
      if (tt + 3 < NT) {
        stage(tt + 3, slot);                 // overwrite freed slot (WAR-safe)
        asm volatile("s_waitcnt vmcnt(6)" ::: "memory");   // tile tt+1 retired
      } else if (tt + 2 < NT) {
        asm volatile("s_waitcnt vmcnt(3)" ::: "memory");   // tt+2 outstanding only
      } else {
        asm volatile("s_waitcnt vmcnt(0)" ::: "memory");   // tt+1 last in flight
      }
      __builtin_amdgcn_s_barrier();          // tile tt+1 visible to all waves
      __builtin_amdgcn_sched_barrier(0);
    }
    slot = (slot == 2) ? 0 : slot + 1;
  }

  // epilogue: C/D layout col=lane&15, row=(lane>>4)*4+jj
  int colg = l15, rowg = g << 2;
  float* C32 = (float*)jb.Cout;
  ushort_t* C16 = (ushort_t*)jb.Cout;
  ushort_t* Cdual = jb.Cdual;
#pragma unroll
  for (int nf = 0; nf < 4; ++nf) {
    int col = n0 + wn * 64 + nf * 16 + colg;
    float bv = jb.bias[col];
#pragma unroll
    for (int mf = 0; mf < 4; ++mf) {
      int row = m0 + wm * 64 + mf * 16 + rowg;
#pragma unroll
      for (int jj = 0; jj < 4; ++jj) {
        float v = fmaxf(acc[mf][nf][jj] + bv, 0.0f);
        if (jb.outF32) C32[(size_t)(row + jj) * 512 + col] = v;
        else           C16[(size_t)(row + jj) * 512 + col] = f2bf(v);
        if (Cdual)     Cdual[(size_t)(row + jj) * 512 + col] = f2bf(v);
      }
    }
  }
}

extern "C" void kernel_launch(void* const* d_in, const int* in_sizes, int n_in,
                              void* d_out, int out_size, void* d_ws, size_t ws_size,
                              hipStream_t stream) {
  (void)n_in; (void)out_size;
  const float* pred = (const float*)d_in[1];
  const float* centroid = (const float*)d_in[4];
  const float* W[8] = { (const float*)d_in[5],  (const float*)d_in[7],  (const float*)d_in[9],
                        (const float*)d_in[11], (const float*)d_in[13], (const float*)d_in[15],
                        (const float*)d_in[17], (const float*)d_in[19] };
  const float* Bv[8] = { (const float*)d_in[6],  (const float*)d_in[8],  (const float*)d_in[10],
                         (const float*)d_in[12], (const float*)d_in[14], (const float*)d_in[16],
                         (const float*)d_in[18], (const float*)d_in[20] };
  int Kd[8] = {512, 512, 640, 512, 512, 512, 1536, 512};
  const float* pos_w1 = (const float*)d_in[21]; const float* pos_b1 = (const float*)d_in[22];
  const float* pos_w2 = (const float*)d_in[23]; const float* pos_b2 = (const float*)d_in[24];
  const float* pos_w3 = (const float*)d_in[25]; const float* pos_b3 = (const float*)d_in[26];

  int E = in_sizes[1] / 512;       // 65280
  int n = in_sizes[4] / 3;         // 256

  char* ws = (char*)d_ws;
  size_t off = 0;
  auto alloc = [&](size_t bytes) -> void* {
    void* p = ws + off;
    off = (off + bytes + 255) & ~(size_t)255;
    return p;
  };
  size_t SB = (size_t)E * 512 * 2;           // one bf16 activation slab (66.8 MB)
  ushort_t* Wt[8];
  for (int i = 0; i < 8; ++i) Wt[i] = (ushort_t*)alloc((size_t)Kd[i] * 512 * 2);
  ushort_t* X = (ushort_t*)alloc(SB);        // bf16 pred; reused as comp16 after dispatch A
  ushort_t* Hb_sup  = (ushort_t*)alloc(SB);  // later reused as link hidden
  ushort_t* Hb_prox = (ushort_t*)alloc(SB);
  ushort_t* Hb_comp = (ushort_t*)alloc(SB);
  ushort_t* sup16_ws  = (ushort_t*)alloc(SB);
  ushort_t* prox16_ws = (ushort_t*)alloc(SB);
  bool fast = (off <= ws_size) && (E % 128 == 0);   // ~407 MB

  float* outF = (float*)d_out;
  size_t S = (size_t)E * 512;
  float* out_link = outF;
  float* out_sup  = outF + S;
  float* out_prox = outF + 2 * S;
  float* out_comp = outF + 3 * S;
  ushort_t* pos = (ushort_t*)d_out;          // slot0 head; only link-L2 overwrites slot0

  TransArgs ta;
  int nblk = 0;
  for (int i = 0; i < 8; ++i) {
    ta.src[i] = W[i]; ta.dst[i] = Wt[i]; ta.K[i] = Kd[i];
    ta.blk0[i] = nblk;
    nblk += (Kd[i] >> 6) * 8;
  }
  ta.blk0[8] = nblk;
  hipLaunchKernelGGL(transpose_weights, dim3(nblk), dim3(256), 0, stream, ta);
  hipLaunchKernelGGL(prep_kernel, dim3(E / 128), dim3(256), 0, stream,
                     pred, centroid, pos_w1, pos_b1, pos_w2, pos_b2, pos_w3, pos_b3,
                     X, pos, n - 1);

  const ushort_t* Zu = nullptr;
  ushort_t* NO16 = nullptr;

  if (fast) {
    int nb = E / 128 * 2;                    // 1020 blocks per job
    dim3 b512(512);
    ushort_t* comp16 = X;                    // X dead after dispatch A
    ushort_t* Hl = Hb_sup;                   // Hb_sup dead after dispatch B

    auto mkjob = [&](const ushort_t* A0, int lda0, const ushort_t* A1, int lda1,
                     const ushort_t* A2, int lda2, int s0, int s1,
                     const ushort_t* Bt, const float* bias,
                     void* Cout, ushort_t* dual, int K, int outF32) {
      GJob j;
      j.A0 = A0; j.A1 = A1; j.A2 = A2; j.Bt = Bt; j.bias = bias;
      j.Cout = Cout; j.Cdual = dual;
      j.lda0 = lda0; j.lda1 = lda1; j.lda2 = lda2;
      j.s0 = s0; j.s1 = s1; j.K = K; j.outF32 = outF32;
      return j;
    };

    // Dispatch A: three branch L1s (all read X; prox also reads pos)
    GJobs JA;
    JA.j[0] = mkjob(X, 512, Zu, 0, Zu, 0, 512, 512, Wt[0], Bv[0], Hb_sup,  NO16, 512, 0);
    JA.j[1] = mkjob(X, 512, pos, 128, Zu, 0, 512, 640, Wt[2], Bv[2], Hb_prox, NO16, 640, 0);
    JA.j[2] = mkjob(X, 512, Zu, 0, Zu, 0, 512, 512, Wt[4], Bv[4], Hb_comp, NO16, 512, 0);
    JA.blk0[0] = 0; JA.blk0[1] = nb; JA.blk0[2] = 2 * nb; JA.blk0[3] = 3 * nb;
    hipLaunchKernelGGL(gemm_jobs, dim3(3 * nb), b512, 0, stream, JA);

    // Dispatch B: three branch L2s (f32 out + bf16 dual)
    GJobs JB;
    JB.j[0] = mkjob(Hb_sup,  512, Zu, 0, Zu, 0, 512, 512, Wt[1], Bv[1], out_sup,  sup16_ws,  512, 1);
    JB.j[1] = mkjob(Hb_prox, 512, Zu, 0, Zu, 0, 512, 512, Wt[3], Bv[3], out_prox, prox16_ws, 512, 1);
    JB.j[2] = mkjob(Hb_comp, 512, Zu, 0, Zu, 0, 512, 512, Wt[5], Bv[5], out_comp, comp16,    512, 1);
    JB.blk0[0] = 0; JB.blk0[1] = nb; JB.blk0[2] = 2 * nb; JB.blk0[3] = 3 * nb;
    hipLaunchKernelGGL(gemm_jobs, dim3(3 * nb), b512, 0, stream, JB);

    // link-L1: segments [sup16 | prox16 | comp16]
    GJobs JC;
    JC.j[0] = mkjob(sup16_ws, 512, prox16_ws, 512, comp16, 512, 512, 1024,
                    Wt[6], Bv[6], Hl, NO16, 1536, 0);
    JC.j[1] = JC.j[0]; JC.j[2] = JC.j[0];
    JC.blk0[0] = 0; JC.blk0[1] = nb; JC.blk0[2] = nb; JC.blk0[3] = nb;
    hipLaunchKernelGGL(gemm_jobs, dim3(nb), b512, 0, stream, JC);

    // link-L2 -> slot0 f32 (pos region finally overwritten here)
    GJobs JD;
    JD.j[0] = mkjob(Hl, 512, Zu, 0, Zu, 0, 512, 512, Wt[7], Bv[7], out_link, NO16, 512, 1);
    JD.j[1] = JD.j[0]; JD.j[2] = JD.j[0];
    JD.blk0[0] = 0; JD.blk0[1] = nb; JD.blk0[2] = nb; JD.blk0[3] = nb;
    hipLaunchKernelGGL(gemm_jobs, dim3(nb), b512, 0, stream, JD);
  } else {
    // Fallback (round-5 passing plan)
    dim3 g(E / 128 * 4), blk(256);
    const void* Z = nullptr;
    ushort_t* Hb = (ushort_t*)((char*)d_out + (size_t)32 * 1024 * 1024);
    ushort_t* Hl = X;
    hipLaunchKernelGGL(gemm_bias_relu, g, blk, 0, stream,
                       (const void*)X, 512, (const void*)pos, 128, Z, 0, 512, 640, 0,
                       Wt[2], Bv[2], (void*)Hb, 0, NO16, 640);
    hipLaunchKernelGGL(gemm_bias_relu, g, blk, 0, stream,
                       (const void*)Hb, 512, Z, 0, Z, 0, 512, 512, 0,
                       Wt[3], Bv[3], (void*)out_prox, 1, NO16, 512);
    hipLaunchKernelGGL(gemm_bias_relu, g, blk, 0, stream,
                       (const void*)X, 512, Z, 0, Z, 0, 512, 512, 0,
                       Wt[0], Bv[0], (void*)Hb, 0, NO16, 512);
    hipLaunchKernelGGL(gemm_bias_relu, g, blk, 0, stream,
                       (const void*)Hb, 512, Z, 0, Z, 0, 512, 512, 0,
                       Wt[1], Bv[1], (void*)out_sup, 1, NO16, 512);
    hipLaunchKernelGGL(gemm_bias_relu, g, blk, 0, stream,
                       (const void*)X, 512, Z, 0, Z, 0, 512, 512, 0,
                       Wt[4], Bv[4], (void*)Hb, 0, NO16, 512);
    hipLaunchKernelGGL(gemm_bias_relu, g, blk, 0, stream,
                       (const void*)Hb, 512, Z, 0, Z, 0, 512, 512, 0,
                       Wt[5], Bv[5], (void*)out_comp, 1, NO16, 512);
    hipLaunchKernelGGL(gemm_bias_relu, g, blk, 0, stream,
                       (const void*)out_sup, 512, (const void*)out_prox, 512,
                       (const void*)out_comp, 512, 512, 1024, 1,
                       Wt[6], Bv[6], (void*)Hl, 0, NO16, 1536);
    hipLaunchKernelGGL(gemm_bias_relu, g, blk, 0, stream,
                       (const void*)Hl, 512, Z, 0, Z, 0, 512, 512, 0,
                       Wt[7], Bv[7], (void*)out_link, 1, NO16, 512);
  }
}

// Round 15
// 752.289 us; speedup vs baseline: 1.0243x; 1.0243x over previous
//
#include <hip/hip_runtime.h>
#include <stdint.h>

typedef unsigned short ushort_t;
typedef __attribute__((ext_vector_type(8))) short short8;
typedef __attribute__((ext_vector_type(8))) unsigned short u16x8;
typedef __attribute__((ext_vector_type(4))) float f32x4;

#define GLOBAL_AS __attribute__((address_space(1)))
#define LDS_AS __attribute__((address_space(3)))

__device__ __forceinline__ ushort_t f2bf(float f) {
  union { float f; uint32_t u; } v; v.f = f;
  uint32_t u = v.u;
  u += 0x7FFFu + ((u >> 16) & 1u);   // round-to-nearest-even
  return (ushort_t)(u >> 16);
}

// XOR swizzle for [R][64] bf16 LDS tiles (128B rows) in prep kernel.
__device__ __forceinline__ int swz(int row, int byteInRow) {
  return (row * 128 + byteInRow) ^ ((row & 7) << 4);
}

// ---------------- weight transpose + bf16 cast: dst[n][k] = bf16(src[k][n]); fout = 512 always
struct TransArgs {
  const float* src[8];
  ushort_t* dst[8];
  int K[8];
  int blk0[9];
};

__global__ __launch_bounds__(256) void transpose_weights(TransArgs ta) {
  __shared__ float tile[64 * 65];
  int b = blockIdx.x;
  int mi = 0;
#pragma unroll
  for (int i = 1; i < 8; ++i) if (b >= ta.blk0[i]) mi = i;
  const float* src = ta.src[mi];
  ushort_t* dst = ta.dst[mi];
  int K = ta.K[mi];
  int rel = b - ta.blk0[mi];
  int ktiles = K >> 6;
  int k0 = (rel % ktiles) << 6;
  int n0 = (rel / ktiles) << 6;
  int t = threadIdx.x;
#pragma unroll
  for (int i = 0; i < 16; ++i) {
    int idx = i * 256 + t;
    int r = idx >> 6, c = idx & 63;
    tile[r * 65 + c] = src[(size_t)(k0 + r) * 512 + (n0 + c)];
  }
  __syncthreads();
#pragma unroll
  for (int i = 0; i < 16; ++i) {
    int idx = i * 256 + t;
    int r = idx >> 6, c = idx & 63;          // r: n-row, c: k-col
    dst[(size_t)(n0 + r) * K + (k0 + c)] = f2bf(tile[c * 65 + r]);
  }
}

// ---------------- prep: X[e][0:512]=bf16(pred); pos[e][0:128] = 3-layer FCN via MFMA.
__global__ __launch_bounds__(256) void prep_kernel(
    const float* __restrict__ pred, const float* __restrict__ centroid,
    const float* __restrict__ pw1, const float* __restrict__ pb1,
    const float* __restrict__ pw2, const float* __restrict__ pb2,
    const float* __restrict__ pw3, const float* __restrict__ pb3,
    ushort_t* __restrict__ X, ushort_t* __restrict__ pos, int nm1)
{
  __shared__ ushort_t h1s[128 * 64];
  __shared__ ushort_t h2s[128 * 64];
  __shared__ ushort_t w2t[64 * 64];
  __shared__ ushort_t w3t[128 * 64];
  __shared__ float w1s[5 * 64];
  __shared__ float b1s[64], b2s[64], b3s[128];
  int t = threadIdx.x;
  for (int idx = t; idx < 64 * 64; idx += 256) {
    int k = idx >> 6, n = idx & 63;
    *(ushort_t*)((char*)w2t + swz(n, k * 2)) = f2bf(pw2[idx]);
  }
  for (int idx = t; idx < 64 * 128; idx += 256) {
    int k = idx >> 7, n = idx & 127;
    *(ushort_t*)((char*)w3t + swz(n, k * 2)) = f2bf(pw3[idx]);
  }
  for (int i = t; i < 5 * 64; i += 256) w1s[i] = pw1[i];
  if (t < 64) { b1s[t] = pb1[t]; b2s[t] = pb2[t]; }
  if (t < 128) b3s[t] = pb3[t];
  __syncthreads();   // race fix (r4)

  int wid = t >> 6, lane = t & 63;
  int ebase = blockIdx.x * 128 + wid * 32;
  for (int it = 0; it < 32; ++it) {
    int e = ebase + it;
    const float* pr = pred + (size_t)e * 512 + lane * 8;
    float4 pA = *(const float4*)pr;
    float4 pB = *(const float4*)(pr + 4);
    u16x8 o;
    o[0] = f2bf(pA.x); o[1] = f2bf(pA.y); o[2] = f2bf(pA.z); o[3] = f2bf(pA.w);
    o[4] = f2bf(pB.x); o[5] = f2bf(pB.y); o[6] = f2bf(pB.z); o[7] = f2bf(pB.w);
    *(u16x8*)(X + (size_t)e * 512 + lane * 8) = o;
    int i = e / nm1;
    int r = e - i * nm1;
    int j = r + (r >= i ? 1 : 0);
    float dx = centroid[i * 3 + 0] - centroid[j * 3 + 0];
    float dy = centroid[i * 3 + 1] - centroid[j * 3 + 1];
    float dist = sqrtf(dx * dx + dy * dy);
    float inv = 1.0f / dist;
    float h1 = w1s[0 * 64 + lane] * dx + w1s[1 * 64 + lane] * dy + w1s[2 * 64 + lane] * dist
             + w1s[3 * 64 + lane] * (dx * inv) + w1s[4 * 64 + lane] * (dy * inv) + b1s[lane];
    h1 = fmaxf(h1, 0.0f);
    int row = wid * 32 + it;
    *(ushort_t*)((char*)h1s + swz(row, lane * 2)) = f2bf(h1);
  }
  __syncthreads();

  int colg = lane & 15, rowg = (lane >> 4) << 2;
  int ko_lane = (lane >> 4) * 8;
  {
    f32x4 acc[2][4];
    f32x4 zero = {0.0f, 0.0f, 0.0f, 0.0f};
#pragma unroll
    for (int m_ = 0; m_ < 2; ++m_)
#pragma unroll
      for (int n_ = 0; n_ < 4; ++n_) acc[m_][n_] = zero;
#pragma unroll
    for (int kk = 0; kk < 2; ++kk) {
      int ko = kk * 32 + ko_lane;
      short8 a[2], b[4];
#pragma unroll
      for (int m_ = 0; m_ < 2; ++m_)
        a[m_] = *(const short8*)((const char*)h1s + swz(wid * 32 + m_ * 16 + colg, ko * 2));
#pragma unroll
      for (int n_ = 0; n_ < 4; ++n_)
        b[n_] = *(const short8*)((const char*)w2t + swz(n_ * 16 + colg, ko * 2));
#pragma unroll
      for (int m_ = 0; m_ < 2; ++m_)
#pragma unroll
        for (int n_ = 0; n_ < 4; ++n_)
          acc[m_][n_] = __builtin_amdgcn_mfma_f32_16x16x32_bf16(a[m_], b[n_], acc[m_][n_], 0, 0, 0);
    }
#pragma unroll
    for (int n_ = 0; n_ < 4; ++n_) {
      int col = n_ * 16 + colg;
      float bv = b2s[col];
#pragma unroll
      for (int m_ = 0; m_ < 2; ++m_) {
        int row = wid * 32 + m_ * 16 + rowg;
#pragma unroll
        for (int jj = 0; jj < 4; ++jj) {
          float v = fmaxf(acc[m_][n_][jj] + bv, 0.0f);
          *(ushort_t*)((char*)h2s + swz(row + jj, col * 2)) = f2bf(v);
        }
      }
    }
  }
  __syncthreads();
  {
    f32x4 acc[2][8];
    f32x4 zero = {0.0f, 0.0f, 0.0f, 0.0f};
#pragma unroll
    for (int m_ = 0; m_ < 2; ++m_)
#pragma unroll
      for (int n_ = 0; n_ < 8; ++n_) acc[m_][n_] = zero;
#pragma unroll
    for (int kk = 0; kk < 2; ++kk) {
      int ko = kk * 32 + ko_lane;
      short8 a[2], b[8];
#pragma unroll
      for (int m_ = 0; m_ < 2; ++m_)
        a[m_] = *(const short8*)((const char*)h2s + swz(wid * 32 + m_ * 16 + colg, ko * 2));
#pragma unroll
      for (int n_ = 0; n_ < 8; ++n_)
        b[n_] = *(const short8*)((const char*)w3t + swz(n_ * 16 + colg, ko * 2));
#pragma unroll
      for (int m_ = 0; m_ < 2; ++m_)
#pragma unroll
        for (int n_ = 0; n_ < 8; ++n_)
          acc[m_][n_] = __builtin_amdgcn_mfma_f32_16x16x32_bf16(a[m_], b[n_], acc[m_][n_], 0, 0, 0);
    }
#pragma unroll
    for (int n_ = 0; n_ < 8; ++n_) {
      int col = n_ * 16 + colg;
      float bv = b3s[col];
#pragma unroll
      for (int m_ = 0; m_ < 2; ++m_) {
        int row = wid * 32 + m_ * 16 + rowg;
#pragma unroll
        for (int jj = 0; jj < 4; ++jj) {
          int e = blockIdx.x * 128 + row + jj;
          pos[(size_t)e * 128 + col] = f2bf(acc[m_][n_][jj] + bv);
        }
      }
    }
  }
}

// ---------------- OLD 128x128 GEMM (fallback path only)
__global__ __launch_bounds__(256) void gemm_bias_relu(
    const void* __restrict__ A0, int lda0,
    const void* __restrict__ A1, int lda1,
    const void* __restrict__ A2, int lda2,
    int s0, int s1, int aF32,
    const ushort_t* __restrict__ Bt, const float* __restrict__ bias,
    void* __restrict__ Cout, int outF32, ushort_t* __restrict__ Cdual, int K)
{
  __shared__ ushort_t As[128 * 64];
  __shared__ ushort_t Bs[128 * 64];
  int bid = blockIdx.x;
  int cpx = gridDim.x >> 3;
  int swzb = (bid & 7) * cpx + (bid >> 3);
  int mt = swzb >> 2, nt = swzb & 3;
  int m0 = mt << 7, n0 = nt << 7;
  int t = threadIdx.x;
  int lane = t & 63, wid = t >> 6;
  int wm = wid >> 1, wn = wid & 1;
  f32x4 acc[4][4];
  f32x4 zero = {0.0f, 0.0f, 0.0f, 0.0f};
#pragma unroll
  for (int a_ = 0; a_ < 4; ++a_)
#pragma unroll
    for (int b_ = 0; b_ < 4; ++b_) acc[a_][b_] = zero;

  for (int kt = 0; kt < K; kt += 64) {
    const void* Ab; int ldaA; int kin;
    if (kt < s0)      { Ab = A0; ldaA = lda0; kin = kt; }
    else if (kt < s1) { Ab = A1; ldaA = lda1; kin = kt - s0; }
    else              { Ab = A2; ldaA = lda2; kin = kt - s1; }
    if (aF32) {
      const float* Af = (const float*)Ab;
      int rr = t >> 1, cc0 = (t & 1) << 5;
      const float* g = Af + (size_t)(m0 + rr) * ldaA + kin + cc0;
      ushort_t* ldst = As + rr * 64 + cc0;
#pragma unroll
      for (int i = 0; i < 4; ++i) {
        float4 v0 = *(const float4*)(g + i * 8);
        float4 v1 = *(const float4*)(g + i * 8 + 4);
        u16x8 o;
        o[0] = f2bf(v0.x); o[1] = f2bf(v0.y); o[2] = f2bf(v0.z); o[3] = f2bf(v0.w);
        o[4] = f2bf(v1.x); o[5] = f2bf(v1.y); o[6] = f2bf(v1.z); o[7] = f2bf(v1.w);
        *(u16x8*)(ldst + i * 8) = o;
      }
    } else {
      const ushort_t* Ah = (const ushort_t*)Ab;
#pragma unroll
      for (int i = 0; i < 4; ++i) {
        int ch = i * 256 + t;
        int rr = ch >> 3, cc = (ch & 7) << 3;
        const ushort_t* g = Ah + (size_t)(m0 + rr) * ldaA + kin + cc;
        __builtin_amdgcn_global_load_lds((const GLOBAL_AS void*)g,
                                         (LDS_AS void*)(As + ch * 8), 16, 0, 0);
      }
    }
#pragma unroll
    for (int i = 0; i < 4; ++i) {
      int ch = i * 256 + t;
      int rr = ch >> 3, cc = (ch & 7) << 3;
      const ushort_t* g = Bt + (size_t)(n0 + rr) * K + kt + cc;
      __builtin_amdgcn_global_load_lds((const GLOBAL_AS void*)g,
                                       (LDS_AS void*)(Bs + ch * 8), 16, 0, 0);
    }
    __syncthreads();
#pragma unroll
    for (int kk = 0; kk < 64; kk += 32) {
      int ko = kk + (lane >> 4) * 8;
      short8 a[4], b[4];
#pragma unroll
      for (int m_ = 0; m_ < 4; ++m_)
        a[m_] = *(const short8*)(As + (wm * 64 + m_ * 16 + (lane & 15)) * 64 + ko);
#pragma unroll
      for (int n_ = 0; n_ < 4; ++n_)
        b[n_] = *(const short8*)(Bs + (wn * 64 + n_ * 16 + (lane & 15)) * 64 + ko);
#pragma unroll
      for (int m_ = 0; m_ < 4; ++m_)
#pragma unroll
        for (int n_ = 0; n_ < 4; ++n_)
          acc[m_][n_] = __builtin_amdgcn_mfma_f32_16x16x32_bf16(a[m_], b[n_], acc[m_][n_], 0, 0, 0);
    }
    __syncthreads();
  }
  int colg = lane & 15, rowg = (lane >> 4) << 2;
  float* C32 = (float*)Cout;
  ushort_t* C16 = (ushort_t*)Cout;
#pragma unroll
  for (int n_ = 0; n_ < 4; ++n_) {
    int col = n0 + wn * 64 + n_ * 16 + colg;
    float bv = bias[col];
#pragma unroll
    for (int m_ = 0; m_ < 4; ++m_) {
      int row = m0 + wm * 64 + m_ * 16 + rowg;
#pragma unroll
      for (int jj = 0; jj < 4; ++jj) {
        float v = fmaxf(acc[m_][n_][jj] + bv, 0.0f);
        if (outF32) C32[(size_t)(row + jj) * 512 + col] = v;
        else        C16[(size_t)(row + jj) * 512 + col] = f2bf(v);
        if (Cdual)  Cdual[(size_t)(row + jj) * 512 + col] = f2bf(v);
      }
    }
  }
}

// ---------------- Multi-job GEMM: the r5/r6-MEASURED 256-thread m97 core.
// 128x128 tile, BK=64, 4 waves (2x2), 32 KiB LDS -> ~5 blocks/CU: many
// independent K-pipelines (TLP latency cover, m114). Measured 57-64 us per
// K=512 job in the round-5 profile -- best per-job datapoint of the session.
// Wrapped in the r13 multi-job harness (job-major blocks, per-job m204
// swizzle). Numerics identical to all passing rounds (ascending 32-slices).
struct GJob {
  const ushort_t* A0; const ushort_t* A1; const ushort_t* A2;
  const ushort_t* Bt; const float* bias;
  void* Cout; ushort_t* Cdual;
  int lda0, lda1, lda2, s0, s1, K, outF32;
};
struct GJobs { GJob j[3]; int blk0[4]; };

__global__ __launch_bounds__(256) void gemm_jobs(GJobs J) {
  __shared__ ushort_t As[128 * 64];
  __shared__ ushort_t Bs[128 * 64];
  int bid = blockIdx.x;
  int ji = 0;
  if (bid >= J.blk0[1]) ji = 1;
  if (bid >= J.blk0[2]) ji = 2;
  const GJob jb = J.j[ji];
  int rel = bid - J.blk0[ji];
  int nwg = J.blk0[ji + 1] - J.blk0[ji];
  int q = nwg >> 3, r8_ = nwg & 7;
  int xcd = rel & 7, ii = rel >> 3;
  int sid = (xcd < r8_ ? xcd * (q + 1) : r8_ * (q + 1) + (xcd - r8_) * q) + ii;
  int mt = sid >> 2, nt = sid & 3;           // 4 n-tiles of 128; consecutive sids share mt
  int m0 = mt << 7, n0 = nt << 7;
  int t = threadIdx.x;
  int lane = t & 63, wid = t >> 6;
  int wm = wid >> 1, wn = wid & 1;           // wave -> 64x64 quadrant
  int K = jb.K;
  f32x4 acc[4][4];
  f32x4 zero = {0.0f, 0.0f, 0.0f, 0.0f};
#pragma unroll
  for (int a_ = 0; a_ < 4; ++a_)
#pragma unroll
    for (int b_ = 0; b_ < 4; ++b_) acc[a_][b_] = zero;

  for (int kt = 0; kt < K; kt += 64) {
    const ushort_t* Ab; int ldaA; int kin;
    if (kt < jb.s0)      { Ab = jb.A0; ldaA = jb.lda0; kin = kt; }
    else if (kt < jb.s1) { Ab = jb.A1; ldaA = jb.lda1; kin = kt - jb.s0; }
    else                 { Ab = jb.A2; ldaA = jb.lda2; kin = kt - jb.s1; }
#pragma unroll
    for (int i = 0; i < 4; ++i) {            // stage A tile: 128 rows x 64 bf16
      int ch = i * 256 + t;
      int rr = ch >> 3, cc = (ch & 7) << 3;
      const ushort_t* g = Ab + (size_t)(m0 + rr) * ldaA + kin + cc;
      __builtin_amdgcn_global_load_lds((const GLOBAL_AS void*)g,
                                       (LDS_AS void*)(As + ch * 8), 16, 0, 0);
    }
#pragma unroll
    for (int i = 0; i < 4; ++i) {            // stage B^T tile: 128 n-rows x 64 bf16
      int ch = i * 256 + t;
      int rr = ch >> 3, cc = (ch & 7) << 3;
      const ushort_t* g = jb.Bt + (size_t)(n0 + rr) * K + kt + cc;
      __builtin_amdgcn_global_load_lds((const GLOBAL_AS void*)g,
                                       (LDS_AS void*)(Bs + ch * 8), 16, 0, 0);
    }
    __syncthreads();                         // compiler drains vmcnt before barrier
#pragma unroll
    for (int kk = 0; kk < 64; kk += 32) {
      int ko = kk + (lane >> 4) * 8;
      short8 a[4], b[4];
#pragma unroll
      for (int m_ = 0; m_ < 4; ++m_)
        a[m_] = *(const short8*)(As + (wm * 64 + m_ * 16 + (lane & 15)) * 64 + ko);
#pragma unroll
      for (int n_ = 0; n_ < 4; ++n_)
        b[n_] = *(const short8*)(Bs + (wn * 64 + n_ * 16 + (lane & 15)) * 64 + ko);
#pragma unroll
      for (int m_ = 0; m_ < 4; ++m_)
#pragma unroll
        for (int n_ = 0; n_ < 4; ++n_)
          acc[m_][n_] = __builtin_amdgcn_mfma_f32_16x16x32_bf16(a[m_], b[n_], acc[m_][n_], 0, 0, 0);
    }
    __syncthreads();
  }
  // epilogue: C/D layout col=lane&15, row=(lane>>4)*4+jj (m89-verified)
  int colg = lane & 15, rowg = (lane >> 4) << 2;
  float* C32 = (float*)jb.Cout;
  ushort_t* C16 = (ushort_t*)jb.Cout;
  ushort_t* Cdual = jb.Cdual;
#pragma unroll
  for (int n_ = 0; n_ < 4; ++n_) {
    int col = n0 + wn * 64 + n_ * 16 + colg;
    float bv = jb.bias[col];
#pragma unroll
    for (int m_ = 0; m_ < 4; ++m_) {
      int row = m0 + wm * 64 + m_ * 16 + rowg;
#pragma unroll
      for (int jj = 0; jj < 4; ++jj) {
        float v = fmaxf(acc[m_][n_][jj] + bv, 0.0f);
        if (jb.outF32) C32[(size_t)(row + jj) * 512 + col] = v;
        else           C16[(size_t)(row + jj) * 512 + col] = f2bf(v);
        if (Cdual)     Cdual[(size_t)(row + jj) * 512 + col] = f2bf(v);
      }
    }
  }
}

extern "C" void kernel_launch(void* const* d_in, const int* in_sizes, int n_in,
                              void* d_out, int out_size, void* d_ws, size_t ws_size,
                              hipStream_t stream) {
  (void)n_in; (void)out_size;
  const float* pred = (const float*)d_in[1];
  const float* centroid = (const float*)d_in[4];
  const float* W[8] = { (const float*)d_in[5],  (const float*)d_in[7],  (const float*)d_in[9],
                        (const float*)d_in[11], (const float*)d_in[13], (const float*)d_in[15],
                        (const float*)d_in[17], (const float*)d_in[19] };
  const float* Bv[8] = { (const float*)d_in[6],  (const float*)d_in[8],  (const float*)d_in[10],
                         (const float*)d_in[12], (const float*)d_in[14], (const float*)d_in[16],
                         (const float*)d_in[18], (const float*)d_in[20] };
  int Kd[8] = {512, 512, 640, 512, 512, 512, 1536, 512};
  const float* pos_w1 = (const float*)d_in[21]; const float* pos_b1 = (const float*)d_in[22];
  const float* pos_w2 = (const float*)d_in[23]; const float* pos_b2 = (const float*)d_in[24];
  const float* pos_w3 = (const float*)d_in[25]; const float* pos_b3 = (const float*)d_in[26];

  int E = in_sizes[1] / 512;       // 65280
  int n = in_sizes[4] / 3;         // 256

  char* ws = (char*)d_ws;
  size_t off = 0;
  auto alloc = [&](size_t bytes) -> void* {
    void* p = ws + off;
    off = (off + bytes + 255) & ~(size_t)255;
    return p;
  };
  size_t SB = (size_t)E * 512 * 2;           // one bf16 activation slab (66.8 MB)
  ushort_t* Wt[8];
  for (int i = 0; i < 8; ++i) Wt[i] = (ushort_t*)alloc((size_t)Kd[i] * 512 * 2);
  ushort_t* X = (ushort_t*)alloc(SB);        // bf16 pred; reused as comp16 after dispatch A
  ushort_t* Hb_sup  = (ushort_t*)alloc(SB);  // later reused as link hidden
  ushort_t* Hb_prox = (ushort_t*)alloc(SB);
  ushort_t* Hb_comp = (ushort_t*)alloc(SB);
  ushort_t* sup16_ws  = (ushort_t*)alloc(SB);
  ushort_t* prox16_ws = (ushort_t*)alloc(SB);
  bool fast = (off <= ws_size) && (E % 128 == 0);   // ~407 MB

  float* outF = (float*)d_out;
  size_t S = (size_t)E * 512;
  float* out_link = outF;
  float* out_sup  = outF + S;
  float* out_prox = outF + 2 * S;
  float* out_comp = outF + 3 * S;
  ushort_t* pos = (ushort_t*)d_out;          // slot0 head; only link-L2 overwrites slot0

  TransArgs ta;
  int nblk = 0;
  for (int i = 0; i < 8; ++i) {
    ta.src[i] = W[i]; ta.dst[i] = Wt[i]; ta.K[i] = Kd[i];
    ta.blk0[i] = nblk;
    nblk += (Kd[i] >> 6) * 8;
  }
  ta.blk0[8] = nblk;
  hipLaunchKernelGGL(transpose_weights, dim3(nblk), dim3(256), 0, stream, ta);
  hipLaunchKernelGGL(prep_kernel, dim3(E / 128), dim3(256), 0, stream,
                     pred, centroid, pos_w1, pos_b1, pos_w2, pos_b2, pos_w3, pos_b3,
                     X, pos, n - 1);

  const ushort_t* Zu = nullptr;
  ushort_t* NO16 = nullptr;

  if (fast) {
    int nb = E / 128 * 4;                    // 2040 blocks per job (128x128 tiles)
    dim3 b256(256);
    ushort_t* comp16 = X;                    // X dead after dispatch A
    ushort_t* Hl = Hb_sup;                   // Hb_sup dead after dispatch B

    auto mkjob = [&](const ushort_t* A0, int lda0, const ushort_t* A1, int lda1,
                     const ushort_t* A2, int lda2, int s0, int s1,
                     const ushort_t* Bt, const float* bias,
                     void* Cout, ushort_t* dual, int K, int outF32) {
      GJob j;
      j.A0 = A0; j.A1 = A1; j.A2 = A2; j.Bt = Bt; j.bias = bias;
      j.Cout = Cout; j.Cdual = dual;
      j.lda0 = lda0; j.lda1 = lda1; j.lda2 = lda2;
      j.s0 = s0; j.s1 = s1; j.K = K; j.outF32 = outF32;
      return j;
    };

    // Dispatch A: three branch L1s (all read X; prox also reads pos)
    GJobs JA;
    JA.j[0] = mkjob(X, 512, Zu, 0, Zu, 0, 512, 512, Wt[0], Bv[0], Hb_sup,  NO16, 512, 0);
    JA.j[1] = mkjob(X, 512, pos, 128, Zu, 0, 512, 640, Wt[2], Bv[2], Hb_prox, NO16, 640, 0);
    JA.j[2] = mkjob(X, 512, Zu, 0, Zu, 0, 512, 512, Wt[4], Bv[4], Hb_comp, NO16, 512, 0);
    JA.blk0[0] = 0; JA.blk0[1] = nb; JA.blk0[2] = 2 * nb; JA.blk0[3] = 3 * nb;
    hipLaunchKernelGGL(gemm_jobs, dim3(3 * nb), b256, 0, stream, JA);

    // Dispatch B: three branch L2s (f32 out + bf16 dual)
    GJobs JB;
    JB.j[0] = mkjob(Hb_sup,  512, Zu, 0, Zu, 0, 512, 512, Wt[1], Bv[1], out_sup,  sup16_ws,  512, 1);
    JB.j[1] = mkjob(Hb_prox, 512, Zu, 0, Zu, 0, 512, 512, Wt[3], Bv[3], out_prox, prox16_ws, 512, 1);
    JB.j[2] = mkjob(Hb_comp, 512, Zu, 0, Zu, 0, 512, 512, Wt[5], Bv[5], out_comp, comp16,    512, 1);
    JB.blk0[0] = 0; JB.blk0[1] = nb; JB.blk0[2] = 2 * nb; JB.blk0[3] = 3 * nb;
    hipLaunchKernelGGL(gemm_jobs, dim3(3 * nb), b256, 0, stream, JB);

    // link-L1: segments [sup16 | prox16 | comp16]
    GJobs JC;
    JC.j[0] = mkjob(sup16_ws, 512, prox16_ws, 512, comp16, 512, 512, 1024,
                    Wt[6], Bv[6], Hl, NO16, 1536, 0);
    JC.j[1] = JC.j[0]; JC.j[2] = JC.j[0];
    JC.blk0[0] = 0; JC.blk0[1] = nb; JC.blk0[2] = nb; JC.blk0[3] = nb;
    hipLaunchKernelGGL(gemm_jobs, dim3(nb), b256, 0, stream, JC);

    // link-L2 -> slot0 f32 (pos region finally overwritten here)
    GJobs JD;
    JD.j[0] = mkjob(Hl, 512, Zu, 0, Zu, 0, 512, 512, Wt[7], Bv[7], out_link, NO16, 512, 1);
    JD.j[1] = JD.j[0]; JD.j[2] = JD.j[0];
    JD.blk0[0] = 0; JD.blk0[1] = nb; JD.blk0[2] = nb; JD.blk0[3] = nb;
    hipLaunchKernelGGL(gemm_jobs, dim3(nb), b256, 0, stream, JD);
  } else {
    // Fallback (round-5 passing plan)
    dim3 g(E / 128 * 4), blk(256);
    const void* Z = nullptr;
    ushort_t* Hb = (ushort_t*)((char*)d_out + (size_t)32 * 1024 * 1024);
    ushort_t* Hl = X;
    hipLaunchKernelGGL(gemm_bias_relu, g, blk, 0, stream,
                       (const void*)X, 512, (const void*)pos, 128, Z, 0, 512, 640, 0,
                       Wt[2], Bv[2], (void*)Hb, 0, NO16, 640);
    hipLaunchKernelGGL(gemm_bias_relu, g, blk, 0, stream,
                       (const void*)Hb, 512, Z, 0, Z, 0, 512, 512, 0,
                       Wt[3], Bv[3], (void*)out_prox, 1, NO16, 512);
    hipLaunchKernelGGL(gemm_bias_relu, g, blk, 0, stream,
                       (const void*)X, 512, Z, 0, Z, 0, 512, 512, 0,
                       Wt[0], Bv[0], (void*)Hb, 0, NO16, 512);
    hipLaunchKernelGGL(gemm_bias_relu, g, blk, 0, stream,
                       (const void*)Hb, 512, Z, 0, Z, 0, 512, 512, 0,
                       Wt[1], Bv[1], (void*)out_sup, 1, NO16, 512);
    hipLaunchKernelGGL(gemm_bias_relu, g, blk, 0, stream,
                       (const void*)X, 512, Z, 0, Z, 0, 512, 512, 0,
                       Wt[4], Bv[4], (void*)Hb, 0, NO16, 512);
    hipLaunchKernelGGL(gemm_bias_relu, g, blk, 0, stream,
                       (const void*)Hb, 512, Z, 0, Z, 0, 512, 512, 0,
                       Wt[5], Bv[5], (void*)out_comp, 1, NO16, 512);
    hipLaunchKernelGGL(gemm_bias_relu, g, blk, 0, stream,
                       (const void*)out_sup, 512, (const void*)out_prox, 512,
                       (const void*)out_comp, 512, 512, 1024, 1,
                       Wt[6], Bv[6], (void*)Hl, 0, NO16, 1536);
    hipLaunchKernelGGL(gemm_bias_relu, g, blk, 0, stream,
                       (const void*)Hl, 512, Z, 0, Z, 0, 512, 512, 0,
                       Wt[7], Bv[7], (void*)out_link, 1, NO16, 512);
  }
}